// Round 4
// baseline (10297.411 us; speedup 1.0000x reference)
//
#include <hip/hip_runtime.h>
#include <math.h>

#define NEGF   (-1e30f)
#define FINTH  (-5e29f)
#define VSZ    32000
#define KBM    5
#define SEQL   34   // T+1 where T = 33
#define NVBLK  1000 // logtop blocks (32 v each)

__device__ __forceinline__ bool cand_gt(float av, int ai, float bv, int bi) {
  return (av > bv) || (av == bv && ai < bi);
}

// top-5 insertion, maintains (tv0..tv4, ti0..ti4) sorted desc by (val, -idx)
#define INS5(xx, ii)                                                           \
  if (cand_gt(xx, ii, tv4, ti4)) {                                             \
    tv4 = xx; ti4 = ii;                                                        \
    if (cand_gt(tv4, ti4, tv3, ti3)) { float tf = tv3; int tj = ti3; tv3 = tv4; ti3 = ti4; tv4 = tf; ti4 = tj; \
      if (cand_gt(tv3, ti3, tv2, ti2)) { tf = tv2; tj = ti2; tv2 = tv3; ti2 = ti3; tv3 = tf; ti3 = tj; \
        if (cand_gt(tv2, ti2, tv1, ti1)) { tf = tv1; tj = ti1; tv1 = tv2; ti1 = ti2; tv2 = tf; ti2 = tj; \
          if (cand_gt(tv1, ti1, tv0, ti0)) { tf = tv0; tj = ti0; tv0 = tv1; ti0 = ti1; tv1 = tf; ti1 = tj; } } } } }

// ---- small sorted-top5 helpers (all loops unrolled -> static indexing) ----
struct T5 { float v[5]; int i[5]; };

__device__ __forceinline__ void t5_init(T5& t) {
  #pragma unroll
  for (int j = 0; j < 5; j++) { t.v[j] = -3.4e38f; t.i[j] = 0x7fffffff; }
}

__device__ __forceinline__ void t5_ins(T5& t, float x, int id) {
  if (cand_gt(x, id, t.v[4], t.i[4])) {
    t.v[4] = x; t.i[4] = id;
    #pragma unroll
    for (int j = 4; j > 0; j--) {
      if (cand_gt(t.v[j], t.i[j], t.v[j-1], t.i[j-1])) {
        float tf = t.v[j-1]; int tj = t.i[j-1];
        t.v[j-1] = t.v[j]; t.i[j-1] = t.i[j];
        t.v[j] = tf; t.i[j] = tj;
      }
    }
  }
}

__device__ __forceinline__ T5 t5_merge(const T5& a, const T5& b) {
  T5 r;
  int i = 0, j = 0;
  #pragma unroll
  for (int o = 0; o < 5; o++) {
    float avv = a.v[i]; int aii = a.i[i];
    float bvv = b.v[j]; int bii = b.i[j];
    bool ta = cand_gt(avv, aii, bvv, bii);
    r.v[o] = ta ? avv : bvv; r.i[o] = ta ? aii : bii;
    i += ta ? 1 : 0; j += ta ? 0 : 1;
  }
  return r;
}

// ---------------- init ----------------
__global__ void init_kernel(float* hb0, int* word_buf, int* hsrc) {
  int i = blockIdx.x * 256 + threadIdx.x;
  if (i < 32 * 512) hb0[i] = 0.f;
  if (i < 160) { word_buf[i] = 0; hsrc[i] = i / KBM; }
}

// ---------------- batched encoder gi: rows r = s*32+b, token = source[b*32+s] ----
// grid (96, 16): j-tile 16, r-tile 64. 256 thr: ng=tid&7 (2 j), mg=tid>>3 (2 rows).
__global__ __launch_bounds__(256, 4) void genc_kernel(
    const float* __restrict__ emb, const int* __restrict__ source,
    const float* __restrict__ Wih, float* __restrict__ gi_enc)
{
  const int tid = threadIdx.x;
  const int ng = tid & 7;
  const int mg = tid >> 3;
  const int j0 = blockIdx.x * 16 + ng * 2;
  const int r0 = blockIdx.y * 64 + mg * 2;

  const float* arow[2];
  #pragma unroll
  for (int i = 0; i < 2; i++) {
    int r = r0 + i;
    int tok = source[(r & 31) * 32 + (r >> 5)];
    arow[i] = emb + (long)tok * 512;
  }
  const float* w0p = Wih + (long)j0 * 512;
  const float* w1p = w0p + 512;

  float acc0[2], acc1[2];
  #pragma unroll
  for (int i = 0; i < 2; i++) { acc0[i] = 0.f; acc1[i] = 0.f; }

  float4 wc0 = *(const float4*)w0p;
  float4 wc1 = *(const float4*)w1p;
  float4 ac[2];
  #pragma unroll
  for (int i = 0; i < 2; i++) ac[i] = *(const float4*)arow[i];

  for (int k = 0; k < 508; k += 4) {
    float4 wn0 = *(const float4*)(w0p + k + 4);
    float4 wn1 = *(const float4*)(w1p + k + 4);
    float4 an[2];
    #pragma unroll
    for (int i = 0; i < 2; i++) an[i] = *(const float4*)(arow[i] + k + 4);
    #pragma unroll
    for (int i = 0; i < 2; i++) {
      acc0[i] += ac[i].x * wc0.x + ac[i].y * wc0.y + ac[i].z * wc0.z + ac[i].w * wc0.w;
      acc1[i] += ac[i].x * wc1.x + ac[i].y * wc1.y + ac[i].z * wc1.z + ac[i].w * wc1.w;
    }
    wc0 = wn0; wc1 = wn1;
    #pragma unroll
    for (int i = 0; i < 2; i++) ac[i] = an[i];
  }
  #pragma unroll
  for (int i = 0; i < 2; i++) {
    acc0[i] += ac[i].x * wc0.x + ac[i].y * wc0.y + ac[i].z * wc0.z + ac[i].w * wc0.w;
    acc1[i] += ac[i].x * wc1.x + ac[i].y * wc1.y + ac[i].z * wc1.z + ac[i].w * wc1.w;
  }
  #pragma unroll
  for (int i = 0; i < 2; i++) {
    float2 r; r.x = acc0[i]; r.y = acc1[i];
    *(float2*)(gi_enc + (long)(r0 + i) * 1536 + j0) = r;
  }
}

// ---------------- gates GEMM, K-split 4, no bias (bias in hupd) ----------------
template<int P, int HONLY>
__global__ __launch_bounds__(256, 4) void gates_kernel(
    const float* __restrict__ emb, const int* __restrict__ tok_ptr, int tok_stride,
    const float* __restrict__ hbuf, const int* __restrict__ hsrc,
    const float* __restrict__ Wih, const float* __restrict__ Whh,
    float* __restrict__ gip, float* __restrict__ ghp)
{
  const bool is_h = HONLY ? true : (blockIdx.y != 0);
  const float* W = is_h ? Whh : Wih;
  const int M = 32 * P;
  float* out = (is_h ? ghp : gip) + (long)blockIdx.z * M * 1536;

  const int tid = threadIdx.x;
  const int ng = tid & 7;
  const int mg = tid >> 3;
  const int j0 = blockIdx.x * 16 + ng * 2;
  const int k0 = blockIdx.z * 128;

  const float* arow[P];
  #pragma unroll
  for (int i = 0; i < P; i++) {
    int m = mg * P + i;
    if (is_h) { int r = hsrc ? hsrc[m] : m; arow[i] = hbuf + (long)r * 512 + k0; }
    else      { int tk = tok_ptr[m * tok_stride]; arow[i] = emb + (long)tk * 512 + k0; }
  }
  const float* w0p = W + (long)j0 * 512 + k0;
  const float* w1p = w0p + 512;

  float acc0[P], acc1[P];
  #pragma unroll
  for (int i = 0; i < P; i++) { acc0[i] = 0.f; acc1[i] = 0.f; }

  float4 wc0 = *(const float4*)w0p;
  float4 wc1 = *(const float4*)w1p;
  float4 ac[P];
  #pragma unroll
  for (int i = 0; i < P; i++) ac[i] = *(const float4*)arow[i];

  for (int k = 0; k < 124; k += 4) {
    float4 wn0 = *(const float4*)(w0p + k + 4);
    float4 wn1 = *(const float4*)(w1p + k + 4);
    float4 an[P];
    #pragma unroll
    for (int i = 0; i < P; i++) an[i] = *(const float4*)(arow[i] + k + 4);
    #pragma unroll
    for (int i = 0; i < P; i++) {
      acc0[i] += ac[i].x * wc0.x + ac[i].y * wc0.y + ac[i].z * wc0.z + ac[i].w * wc0.w;
      acc1[i] += ac[i].x * wc1.x + ac[i].y * wc1.y + ac[i].z * wc1.z + ac[i].w * wc1.w;
    }
    wc0 = wn0; wc1 = wn1;
    #pragma unroll
    for (int i = 0; i < P; i++) ac[i] = an[i];
  }
  #pragma unroll
  for (int i = 0; i < P; i++) {
    acc0[i] += ac[i].x * wc0.x + ac[i].y * wc0.y + ac[i].z * wc0.z + ac[i].w * wc0.w;
    acc1[i] += ac[i].x * wc1.x + ac[i].y * wc1.y + ac[i].z * wc1.z + ac[i].w * wc1.w;
  }
  #pragma unroll
  for (int i = 0; i < P; i++) {
    int m = mg * P + i;
    float2 r; r.x = acc0[i]; r.y = acc1[i];
    *(float2*)(out + (long)m * 1536 + j0) = r;
  }
}

// ---------------- GRU elementwise update (sums K-split partials, adds biases) ----
template<int NPI, int NPH, int M>
__global__ __launch_bounds__(256) void hupd_kernel(
    const float* __restrict__ gip, const float* __restrict__ ghp,
    const float* __restrict__ bih, const float* __restrict__ bhh,
    const float* __restrict__ hin, const int* __restrict__ hsrc,
    float* __restrict__ hout)
{
  int idx = blockIdx.x * 256 + threadIdx.x;
  if (idx >= M * 512) return;
  int m = idx >> 9, i = idx & 511;
  float ir = 0.f, iz = 0.f, inn = 0.f, hr = 0.f, hz = 0.f, hn = 0.f;
  #pragma unroll
  for (int p = 0; p < NPI; p++) {
    const float* g = gip + (long)p * M * 1536 + (long)m * 1536;
    ir += g[i]; iz += g[512 + i]; inn += g[1024 + i];
  }
  #pragma unroll
  for (int p = 0; p < NPH; p++) {
    const float* g = ghp + (long)p * M * 1536 + (long)m * 1536;
    hr += g[i]; hz += g[512 + i]; hn += g[1024 + i];
  }
  ir += bih[i]; iz += bih[512 + i]; inn += bih[1024 + i];
  hr += bhh[i]; hz += bhh[512 + i]; hn += bhh[1024 + i];
  float r = 1.f / (1.f + expf(-(ir + hr)));
  float z = 1.f / (1.f + expf(-(iz + hz)));
  float n = tanhf(inn + r * hn);
  int src = hsrc ? hsrc[m] : m;
  float h = hin[(long)src * 512 + i];
  hout[(long)m * 512 + i] = (1.f - z) * n + z * h;
}

// ---------------- fused logits + per-block (lse-partial, top5-partial) ----------
// grid NVBLK=1000 (32 v each). W staged via global_load_lds double-buffered tiles.
// Partials packed 16 floats (64B) per (blk,row): {m,s,v0..4,i0..4,pad3}.
__global__ __launch_bounds__(256, 4) void logtop_kernel(
    const float* __restrict__ h1, const float* __restrict__ Wout,
    const float* __restrict__ bout, float* __restrict__ PK)
{
  const int tid = threadIdx.x;
  const int ng = tid & 7;
  const int mg = tid >> 3;
  const int blk = blockIdx.x;
  const int v0 = blk * 32;
  const int v = v0 + ng * 4;
  const int m0 = mg * 5;

  __shared__ float Wlds[2][2048];   // [buf][64 k rows x 32 v]
  __shared__ float L[160][33];

  const float* a0 = h1 + (long)m0 * 512;

  const int skk = tid >> 3;
  const int sv4 = tid & 7;
  const float* sg0 = Wout + (size_t)skk * VSZ + v0 + sv4 * 4;
  const float* sg1 = Wout + (size_t)(32 + skk) * VSZ + v0 + sv4 * 4;
  const int lwave = (tid >> 6) * 256;   // this wave's 1KB chunk (in floats)

  auto stage = [&](int tt, int bb) {
    const float* g0 = sg0 + (size_t)tt * 64 * VSZ;
    const float* g1 = sg1 + (size_t)tt * 64 * VSZ;
    __builtin_amdgcn_global_load_lds(
        (const __attribute__((address_space(1))) void*)g0,
        (__attribute__((address_space(3))) void*)&Wlds[bb][lwave], 16, 0, 0);
    __builtin_amdgcn_global_load_lds(
        (const __attribute__((address_space(1))) void*)g1,
        (__attribute__((address_space(3))) void*)&Wlds[bb][1024 + lwave], 16, 0, 0);
  };

  float4 acc[5];
  #pragma unroll
  for (int i = 0; i < 5; i++) acc[i] = make_float4(0.f, 0.f, 0.f, 0.f);

  stage(0, 0);
  __syncthreads();   // drains vmcnt(0) -> tile 0 resident

  float4 aA[5], aB[5];
  #pragma unroll
  for (int i = 0; i < 5; i++) aA[i] = *(const float4*)(a0 + i * 512);

  for (int t8 = 0; t8 < 8; t8++) {
    const float* lb = &Wlds[t8 & 1][0];
    if (t8 < 7) stage(t8 + 1, (t8 + 1) & 1);
    const int kt = t8 * 64;
    #pragma unroll 1
    for (int c = 0; c < 16; c += 2) {
      const int k = kt + c * 4;
      float4 w0[4], w1[4];
      #pragma unroll
      for (int j = 0; j < 4; j++) w0[j] = *(const float4*)&lb[(c * 4 + j) * 32 + ng * 4];
      #pragma unroll
      for (int j = 0; j < 4; j++) w1[j] = *(const float4*)&lb[(c * 4 + 4 + j) * 32 + ng * 4];
      #pragma unroll
      for (int i = 0; i < 5; i++) aB[i] = *(const float4*)(a0 + i * 512 + k + 4);
      #pragma unroll
      for (int i = 0; i < 5; i++) {
        acc[i].x += aA[i].x * w0[0].x + aA[i].y * w0[1].x + aA[i].z * w0[2].x + aA[i].w * w0[3].x;
        acc[i].y += aA[i].x * w0[0].y + aA[i].y * w0[1].y + aA[i].z * w0[2].y + aA[i].w * w0[3].y;
        acc[i].z += aA[i].x * w0[0].z + aA[i].y * w0[1].z + aA[i].z * w0[2].z + aA[i].w * w0[3].z;
        acc[i].w += aA[i].x * w0[0].w + aA[i].y * w0[1].w + aA[i].z * w0[2].w + aA[i].w * w0[3].w;
      }
      int kn = k + 8; if (kn >= 512) kn = 0;   // dummy re-read on last body
      #pragma unroll
      for (int i = 0; i < 5; i++) aA[i] = *(const float4*)(a0 + i * 512 + kn);
      #pragma unroll
      for (int i = 0; i < 5; i++) {
        acc[i].x += aB[i].x * w1[0].x + aB[i].y * w1[1].x + aB[i].z * w1[2].x + aB[i].w * w1[3].x;
        acc[i].y += aB[i].x * w1[0].y + aB[i].y * w1[1].y + aB[i].z * w1[2].y + aB[i].w * w1[3].y;
        acc[i].z += aB[i].x * w1[0].z + aB[i].y * w1[1].z + aB[i].z * w1[2].z + aB[i].w * w1[3].z;
        acc[i].w += aB[i].x * w1[0].w + aB[i].y * w1[1].w + aB[i].z * w1[2].w + aB[i].w * w1[3].w;
      }
    }
    __syncthreads();   // staging for t8+1 landed during the 16-chunk compute
  }

  float4 bb4 = *(const float4*)(bout + v);
  #pragma unroll
  for (int i = 0; i < 5; i++) {
    L[m0 + i][ng * 4 + 0] = acc[i].x + bb4.x;
    L[m0 + i][ng * 4 + 1] = acc[i].y + bb4.y;
    L[m0 + i][ng * 4 + 2] = acc[i].z + bb4.z;
    L[m0 + i][ng * 4 + 3] = acc[i].w + bb4.w;
  }
  __syncthreads();

  if (tid < 160) {
    float m = -3.4e38f, s = 0.f;
    float tv0 = -3.4e38f, tv1 = -3.4e38f, tv2 = -3.4e38f, tv3 = -3.4e38f, tv4 = -3.4e38f;
    int ti0 = 0x7fffffff, ti1 = 0x7fffffff, ti2 = 0x7fffffff, ti3 = 0x7fffffff, ti4 = 0x7fffffff;
    int base = blk * 32;
    for (int c = 0; c < 32; c++) {
      float x = L[tid][c];
      if (x > m) { s *= expf(m - x); m = x; }
      s += expf(x - m);
      INS5(x, base + c);
    }
    float* pk = PK + ((long)blk * 160 + tid) * 16;
    float4 q0 = make_float4(m, s, tv0, tv1);
    float4 q1 = make_float4(tv2, tv3, tv4, __int_as_float(ti0));
    float4 q2 = make_float4(__int_as_float(ti1), __int_as_float(ti2),
                            __int_as_float(ti3), __int_as_float(ti4));
    *(float4*)(pk + 0) = q0;
    *(float4*)(pk + 4) = q1;
    *(float4*)(pk + 8) = q2;
  }
}

// ---------------- fused merge (1000 partials/row) + bookkeeping ----------------
// grid 32 (one per sentence). NR=1: step-0 (row b*5, a=0). NR=5: steps >=1.
// lse reduction order bit-identical to previous merge: per-thread sequential
// blk=tid,+256,.., shfl_xor wave tree, then sequential 4-wave combine.
template<int NR>
__global__ __launch_bounds__(256) void mergebook_kernel(
    const float* __restrict__ PK,
    const int* __restrict__ seqs_old, int* __restrict__ seqs_new,
    float* __restrict__ act_ll, int* __restrict__ word_buf,
    int* __restrict__ hsrc, float* __restrict__ best_ll,
    int* __restrict__ best_seq, int t)
{
  const int b = blockIdx.x, tid = threadIdx.x;

  float m_[NR], s_[NR];
  T5 t5[NR];
  #pragma unroll
  for (int k = 0; k < NR; k++) { m_[k] = -3.4e38f; s_[k] = 0.f; t5_init(t5[k]); }

  for (int it = 0; it < 4; it++) {
    int blk = tid + it * 256;
    if (blk >= NVBLK) break;
    #pragma unroll
    for (int k = 0; k < NR; k++) {
      const float* pk = PK + ((long)blk * 160 + b * KBM + k) * 16;
      float4 q0 = *(const float4*)(pk + 0);
      float4 q1 = *(const float4*)(pk + 4);
      float4 q2 = *(const float4*)(pk + 8);
      float nm = fmaxf(m_[k], q0.x);
      s_[k] = s_[k] * expf(m_[k] - nm) + q0.y * expf(q0.x - nm);
      m_[k] = nm;
      t5_ins(t5[k], q0.z, __float_as_int(q1.w));
      t5_ins(t5[k], q0.w, __float_as_int(q2.x));
      t5_ins(t5[k], q1.x, __float_as_int(q2.y));
      t5_ins(t5[k], q1.y, __float_as_int(q2.z));
      t5_ins(t5[k], q1.z, __float_as_int(q2.w));
    }
  }

  #pragma unroll
  for (int k = 0; k < NR; k++) {
    float m = m_[k], s = s_[k];
    for (int mask = 1; mask < 64; mask <<= 1) {
      float om = __shfl_xor(m, mask, 64);
      float os = __shfl_xor(s, mask, 64);
      float nm = fmaxf(m, om);
      s = s * expf(m - nm) + os * expf(om - nm);
      m = nm;
    }
    m_[k] = m; s_[k] = s;
    for (int mask = 1; mask < 64; mask <<= 1) {
      T5 o;
      #pragma unroll
      for (int j = 0; j < 5; j++) {
        o.v[j] = __shfl_xor(t5[k].v[j], mask, 64);
        o.i[j] = __shfl_xor(t5[k].i[j], mask, 64);
      }
      t5[k] = t5_merge(t5[k], o);
    }
  }

  __shared__ float wm[KBM][4], wss[KBM][4], wv[KBM][4][5];
  __shared__ int   wi[KBM][4][5];
  __shared__ float sv5[5];
  __shared__ int   si5[5];
  const int wave = tid >> 6;
  if ((tid & 63) == 0) {
    #pragma unroll
    for (int k = 0; k < NR; k++) {
      wm[k][wave] = m_[k]; wss[k][wave] = s_[k];
      #pragma unroll
      for (int j = 0; j < 5; j++) { wv[k][wave][j] = t5[k].v[j]; wi[k][wave][j] = t5[k].i[j]; }
    }
  }
  __syncthreads();

  if (tid == 0) {
    T5 g; t5_init(g);
    #pragma unroll
    for (int k = 0; k < NR; k++) {
      float M2 = wm[k][0], S2 = wss[k][0];
      #pragma unroll
      for (int w = 1; w < 4; w++) {
        float nm = fmaxf(M2, wm[k][w]);
        S2 = S2 * expf(M2 - nm) + wss[k][w] * expf(wm[k][w] - nm);
        M2 = nm;
      }
      float l = M2 + logf(S2);
      T5 rk;
      #pragma unroll
      for (int j = 0; j < 5; j++) { rk.v[j] = wv[k][0][j]; rk.i[j] = wi[k][0][j]; }
      #pragma unroll
      for (int w = 1; w < 4; w++) {
        T5 o;
        #pragma unroll
        for (int j = 0; j < 5; j++) { o.v[j] = wv[k][w][j]; o.i[j] = wi[k][w][j]; }
        rk = t5_merge(rk, o);
      }
      float a = (NR == 1) ? 0.f : act_ll[b * KBM + k];
      #pragma unroll
      for (int j = 0; j < 5; j++) {
        t5_ins(g, a + (rk.v[j] - l), k * VSZ + rk.i[j]);
      }
    }
    #pragma unroll
    for (int j = 0; j < 5; j++) { sv5[j] = g.v[j]; si5[j] = g.i[j]; }
  }
  __syncthreads();

  if (NR == 1) {
    // ---- step-0 bookkeeping ----
    if (tid < SEQL) {
      #pragma unroll
      for (int j = 0; j < KBM; j++) {
        int w = si5[j];   // id = 0*VSZ + word
        seqs_new[(b * KBM + j) * SEQL + tid] = (tid == 0) ? 0 : (tid == 1 ? w : 2);
      }
      best_seq[b * SEQL + tid] = 2;
    }
    if (tid < KBM) {
      act_ll[b * KBM + tid] = sv5[tid];
      word_buf[b * KBM + tid] = si5[tid];
      hsrc[b * KBM + tid] = b * KBM + tid;
    }
    if (tid == 0) best_ll[b] = NEGF;
  } else {
    // ---- per-step bookkeeping ----
    __shared__ int ls[KBM][SEQL];
    float v[KBM]; int pr[KBM], wd[KBM];
    #pragma unroll
    for (int j = 0; j < KBM; j++) {
      v[j] = sv5[j];
      int id = si5[j];
      pr[j] = id / VSZ; wd[j] = id % VSZ;
    }
    #pragma unroll
    for (int j = 0; j < KBM; j++) {
      if (tid < SEQL) {
        int x = (tid == t + 1) ? wd[j] : seqs_old[(b * KBM + pr[j]) * SEQL + tid];
        ls[j][tid] = x;
        seqs_new[(b * KBM + j) * SEQL + tid] = x;
      }
    }
    __syncthreads();
    float cll[KBM];
    #pragma unroll
    for (int j = 0; j < KBM; j++) {
      bool fin = v[j] > FINTH;
      bool eos = (wd[j] == 1) && fin;
      cll[j] = eos ? v[j] / (float)(t + 2) : NEGF;
    }
    int jb = 0; float cb = cll[0];
    #pragma unroll
    for (int j = 1; j < KBM; j++) if (cll[j] > cb) { cb = cll[j]; jb = j; }
    bool improve = cb > best_ll[b];
    if (improve) {
      if (tid == 0) best_ll[b] = cb;
      if (tid < SEQL) best_seq[b * SEQL + tid] = ls[jb][tid];
    }
    if (tid < KBM) {
      int j = tid;
      bool fin = v[j] > FINTH;
      bool eos = (wd[j] == 1) && fin;
      act_ll[b * KBM + j] = (fin && !eos) ? v[j] : NEGF;
      word_buf[b * KBM + j] = wd[j];
      hsrc[b * KBM + j] = b * KBM + pr[j];
    }
  }
}

// ---------------- winner selection ----------------
__global__ void final_kernel(const float* __restrict__ best_ll, const int* __restrict__ best_seq,
                             const float* __restrict__ act_ll, const int* __restrict__ seqs,
                             int* __restrict__ out)
{
  int b = blockIdx.x, tid = threadIdx.x;
  bool have = best_ll[b] > FINTH;
  int jb = 0; float ab = act_ll[b * KBM];
  for (int j = 1; j < KBM; j++)
    if (act_ll[b * KBM + j] > ab) { ab = act_ll[b * KBM + j]; jb = j; }
  if (tid < SEQL)
    out[b * SEQL + tid] = have ? best_seq[b * SEQL + tid]
                               : seqs[(b * KBM + jb) * SEQL + tid];
}

extern "C" void kernel_launch(void* const* d_in, const int* in_sizes, int n_in,
                              void* d_out, int out_size, void* d_ws, size_t ws_size,
                              hipStream_t stream)
{
  const int*   source  = (const int*)d_in[0];
  const float* emb_src = (const float*)d_in[1];
  const float* emb_tgt = (const float*)d_in[2];
  const float* eWih = (const float*)d_in[3];
  const float* eWhh = (const float*)d_in[4];
  const float* ebih = (const float*)d_in[5];
  const float* ebhh = (const float*)d_in[6];
  const float* dWih = (const float*)d_in[7];
  const float* dWhh = (const float*)d_in[8];
  const float* dbih = (const float*)d_in[9];
  const float* dbhh = (const float*)d_in[10];
  const float* Wout = (const float*)d_in[11];
  const float* bout = (const float*)d_in[12];
  int* out = (int*)d_out;

  char* ws = (char*)d_ws;
  size_t off = 0;
  auto alloc = [&](size_t bytes) {
    void* p = ws + off;
    off = (off + bytes + 255) & ~(size_t)255;
    return p;
  };
  float* hb0     = (float*)alloc(160 * 512 * 4);
  float* hb1     = (float*)alloc(160 * 512 * 4);
  float* gip     = (float*)alloc((size_t)4 * 160 * 1536 * 4);
  float* ghp     = (float*)alloc((size_t)4 * 160 * 1536 * 4);
  char*  uni     = (char*) alloc((size_t)11 * 1024 * 1024);  // gi_enc aliases PK
  float* gi_enc  = (float*)uni;                              // 1024*1536*4 = 6.29 MB
  float* PK      = (float*)uni;                              // 1000*160*16*4 = 10.24 MB
  float* act_ll  = (float*)alloc(160 * 4);
  float* best_ll = (float*)alloc(32 * 4);
  int*   seqs0   = (int*)alloc(160 * SEQL * 4);
  int*   seqs1   = (int*)alloc(160 * SEQL * 4);
  int*   wordb   = (int*)alloc(160 * 4);
  int*   hsrc    = (int*)alloc(160 * 4);
  int*   bseq    = (int*)alloc(32 * SEQL * 4);

  init_kernel<<<64, 256, 0, stream>>>(hb0, wordb, hsrc);

  // ---- encoder: batched gi for all 32 steps, then serial gh + update ----
  genc_kernel<<<dim3(96, 16), 256, 0, stream>>>(emb_src, source, eWih, gi_enc);
  for (int s = 0; s < 32; s++) {
    gates_kernel<1, 1><<<dim3(96, 1, 4), 256, 0, stream>>>(
        nullptr, nullptr, 0, hb0, nullptr, nullptr, eWhh, nullptr, ghp);
    hupd_kernel<1, 4, 32><<<64, 256, 0, stream>>>(
        gi_enc + (size_t)s * 32 * 1536, ghp, ebih, ebhh, hb0, nullptr, hb0);
  }

  // ---- decode step 0 (initial advance) ----
  gates_kernel<5, 0><<<dim3(96, 2, 4), 256, 0, stream>>>(
      emb_tgt, wordb, 1, hb0, hsrc, dWih, dWhh, gip, ghp);
  hupd_kernel<4, 4, 160><<<320, 256, 0, stream>>>(
      gip, ghp, dbih, dbhh, hb0, hsrc, hb1);
  logtop_kernel<<<NVBLK, 256, 0, stream>>>(hb1, Wout, bout, PK);
  mergebook_kernel<1><<<32, 256, 0, stream>>>(PK, seqs0, seqs0, act_ll, wordb,
                                              hsrc, best_ll, bseq, 0);

  // ---- decode steps t = 1..32 ----
  float* hcur = hb1; float* hoth = hb0;
  int* scur = seqs0; int* soth = seqs1;
  for (int t = 1; t <= 32; t++) {
    gates_kernel<5, 0><<<dim3(96, 2, 4), 256, 0, stream>>>(
        emb_tgt, wordb, 1, hcur, hsrc, dWih, dWhh, gip, ghp);
    hupd_kernel<4, 4, 160><<<320, 256, 0, stream>>>(
        gip, ghp, dbih, dbhh, hcur, hsrc, hoth);
    logtop_kernel<<<NVBLK, 256, 0, stream>>>(hoth, Wout, bout, PK);
    mergebook_kernel<5><<<32, 256, 0, stream>>>(PK, scur, soth, act_ll, wordb,
                                                hsrc, best_ll, bseq, t);
    { float* tmp = hcur; hcur = hoth; hoth = tmp; }
    { int* tmp = scur; scur = soth; soth = tmp; }
  }

  final_kernel<<<32, 64, 0, stream>>>(best_ll, bseq, act_ll, scur, out);
}

// Round 5
// 7119.856 us; speedup vs baseline: 1.4463x; 1.4463x over previous
//
#include <hip/hip_runtime.h>
#include <math.h>

#define NEGF   (-1e30f)
#define FINTH  (-5e29f)
#define VSZ    32000
#define KBM    5
#define SEQL   34   // T+1 where T = 33
#define NVBLK  1000 // logtop blocks (32 v each)

__device__ __forceinline__ bool cand_gt(float av, int ai, float bv, int bi) {
  return (av > bv) || (av == bv && ai < bi);
}

// top-5 insertion, maintains (tv0..tv4, ti0..ti4) sorted desc by (val, -idx)
#define INS5(xx, ii)                                                           \
  if (cand_gt(xx, ii, tv4, ti4)) {                                             \
    tv4 = xx; ti4 = ii;                                                        \
    if (cand_gt(tv4, ti4, tv3, ti3)) { float tf = tv3; int tj = ti3; tv3 = tv4; ti3 = ti4; tv4 = tf; ti4 = tj; \
      if (cand_gt(tv3, ti3, tv2, ti2)) { tf = tv2; tj = ti2; tv2 = tv3; ti2 = ti3; tv3 = tf; ti3 = tj; \
        if (cand_gt(tv2, ti2, tv1, ti1)) { tf = tv1; tj = ti1; tv1 = tv2; ti1 = ti2; tv2 = tf; ti2 = tj; \
          if (cand_gt(tv1, ti1, tv0, ti0)) { tf = tv0; tj = ti0; tv0 = tv1; ti0 = ti1; tv1 = tf; ti1 = tj; } } } } }

// ---- small sorted-top5 helpers (all loops unrolled -> static indexing) ----
struct T5 { float v[5]; int i[5]; };

__device__ __forceinline__ void t5_init(T5& t) {
  #pragma unroll
  for (int j = 0; j < 5; j++) { t.v[j] = -3.4e38f; t.i[j] = 0x7fffffff; }
}

__device__ __forceinline__ void t5_ins(T5& t, float x, int id) {
  if (cand_gt(x, id, t.v[4], t.i[4])) {
    t.v[4] = x; t.i[4] = id;
    #pragma unroll
    for (int j = 4; j > 0; j--) {
      if (cand_gt(t.v[j], t.i[j], t.v[j-1], t.i[j-1])) {
        float tf = t.v[j-1]; int tj = t.i[j-1];
        t.v[j-1] = t.v[j]; t.i[j-1] = t.i[j];
        t.v[j] = tf; t.i[j] = tj;
      }
    }
  }
}

__device__ __forceinline__ T5 t5_merge(const T5& a, const T5& b) {
  T5 r;
  int i = 0, j = 0;
  #pragma unroll
  for (int o = 0; o < 5; o++) {
    float avv = a.v[i]; int aii = a.i[i];
    float bvv = b.v[j]; int bii = b.i[j];
    bool ta = cand_gt(avv, aii, bvv, bii);
    r.v[o] = ta ? avv : bvv; r.i[o] = ta ? aii : bii;
    i += ta ? 1 : 0; j += ta ? 0 : 1;
  }
  return r;
}

// ---------------- init ----------------
__global__ void init_kernel(float* hb0, int* word_buf, int* hsrc) {
  int i = blockIdx.x * 256 + threadIdx.x;
  if (i < 32 * 512) hb0[i] = 0.f;
  if (i < 160) { word_buf[i] = 0; hsrc[i] = i / KBM; }
}

// ---------------- batched encoder gi: rows r = s*32+b, token = source[b*32+s] ----
// grid (96, 8): j-tile 16, r-tile 128. 256 thr: ng=tid&7 (2 j), mg=tid>>3 (4 rows).
__global__ __launch_bounds__(256, 4) void genc_kernel(
    const float* __restrict__ emb, const int* __restrict__ source,
    const float* __restrict__ Wih, float* __restrict__ gi_enc)
{
  const int tid = threadIdx.x;
  const int ng = tid & 7;
  const int mg = tid >> 3;
  const int j0 = blockIdx.x * 16 + ng * 2;
  const int r0 = blockIdx.y * 128 + mg * 4;

  const float* arow[4];
  #pragma unroll
  for (int i = 0; i < 4; i++) {
    int r = r0 + i;
    int tok = source[(r & 31) * 32 + (r >> 5)];
    arow[i] = emb + (long)tok * 512;
  }
  const float* w0p = Wih + (long)j0 * 512;
  const float* w1p = w0p + 512;

  float acc0[4], acc1[4];
  #pragma unroll
  for (int i = 0; i < 4; i++) { acc0[i] = 0.f; acc1[i] = 0.f; }

  float4 wc0 = *(const float4*)w0p;
  float4 wc1 = *(const float4*)w1p;
  float4 ac[4];
  #pragma unroll
  for (int i = 0; i < 4; i++) ac[i] = *(const float4*)arow[i];

  for (int k = 0; k < 508; k += 4) {
    float4 wn0 = *(const float4*)(w0p + k + 4);
    float4 wn1 = *(const float4*)(w1p + k + 4);
    float4 an[4];
    #pragma unroll
    for (int i = 0; i < 4; i++) an[i] = *(const float4*)(arow[i] + k + 4);
    #pragma unroll
    for (int i = 0; i < 4; i++) {
      acc0[i] += ac[i].x * wc0.x + ac[i].y * wc0.y + ac[i].z * wc0.z + ac[i].w * wc0.w;
      acc1[i] += ac[i].x * wc1.x + ac[i].y * wc1.y + ac[i].z * wc1.z + ac[i].w * wc1.w;
    }
    wc0 = wn0; wc1 = wn1;
    #pragma unroll
    for (int i = 0; i < 4; i++) ac[i] = an[i];
  }
  #pragma unroll
  for (int i = 0; i < 4; i++) {
    acc0[i] += ac[i].x * wc0.x + ac[i].y * wc0.y + ac[i].z * wc0.z + ac[i].w * wc0.w;
    acc1[i] += ac[i].x * wc1.x + ac[i].y * wc1.y + ac[i].z * wc1.z + ac[i].w * wc1.w;
  }
  #pragma unroll
  for (int i = 0; i < 4; i++) {
    float2 r; r.x = acc0[i]; r.y = acc1[i];
    *(float2*)(gi_enc + (long)(r0 + i) * 1536 + j0) = r;
  }
}

// ---------------- gates GEMM, K-split 4, no bias (bias in hupd) ----------------
template<int P, int HONLY>
__global__ __launch_bounds__(256, 4) void gates_kernel(
    const float* __restrict__ emb, const int* __restrict__ tok_ptr, int tok_stride,
    const float* __restrict__ hbuf, const int* __restrict__ hsrc,
    const float* __restrict__ Wih, const float* __restrict__ Whh,
    float* __restrict__ gip, float* __restrict__ ghp)
{
  const bool is_h = HONLY ? true : (blockIdx.y != 0);
  const float* W = is_h ? Whh : Wih;
  const int M = 32 * P;
  float* out = (is_h ? ghp : gip) + (long)blockIdx.z * M * 1536;

  const int tid = threadIdx.x;
  const int ng = tid & 7;
  const int mg = tid >> 3;
  const int j0 = blockIdx.x * 16 + ng * 2;
  const int k0 = blockIdx.z * 128;

  const float* arow[P];
  #pragma unroll
  for (int i = 0; i < P; i++) {
    int m = mg * P + i;
    if (is_h) { int r = hsrc ? hsrc[m] : m; arow[i] = hbuf + (long)r * 512 + k0; }
    else      { int tk = tok_ptr[m * tok_stride]; arow[i] = emb + (long)tk * 512 + k0; }
  }
  const float* w0p = W + (long)j0 * 512 + k0;
  const float* w1p = w0p + 512;

  float acc0[P], acc1[P];
  #pragma unroll
  for (int i = 0; i < P; i++) { acc0[i] = 0.f; acc1[i] = 0.f; }

  float4 wc0 = *(const float4*)w0p;
  float4 wc1 = *(const float4*)w1p;
  float4 ac[P];
  #pragma unroll
  for (int i = 0; i < P; i++) ac[i] = *(const float4*)arow[i];

  for (int k = 0; k < 124; k += 4) {
    float4 wn0 = *(const float4*)(w0p + k + 4);
    float4 wn1 = *(const float4*)(w1p + k + 4);
    float4 an[P];
    #pragma unroll
    for (int i = 0; i < P; i++) an[i] = *(const float4*)(arow[i] + k + 4);
    #pragma unroll
    for (int i = 0; i < P; i++) {
      acc0[i] += ac[i].x * wc0.x + ac[i].y * wc0.y + ac[i].z * wc0.z + ac[i].w * wc0.w;
      acc1[i] += ac[i].x * wc1.x + ac[i].y * wc1.y + ac[i].z * wc1.z + ac[i].w * wc1.w;
    }
    wc0 = wn0; wc1 = wn1;
    #pragma unroll
    for (int i = 0; i < P; i++) ac[i] = an[i];
  }
  #pragma unroll
  for (int i = 0; i < P; i++) {
    acc0[i] += ac[i].x * wc0.x + ac[i].y * wc0.y + ac[i].z * wc0.z + ac[i].w * wc0.w;
    acc1[i] += ac[i].x * wc1.x + ac[i].y * wc1.y + ac[i].z * wc1.z + ac[i].w * wc1.w;
  }
  #pragma unroll
  for (int i = 0; i < P; i++) {
    int m = mg * P + i;
    float2 r; r.x = acc0[i]; r.y = acc1[i];
    *(float2*)(out + (long)m * 1536 + j0) = r;
  }
}

// ---------------- GRU elementwise update (sums K-split partials, adds biases) ----
template<int NPI, int NPH, int M>
__global__ __launch_bounds__(256) void hupd_kernel(
    const float* __restrict__ gip, const float* __restrict__ ghp,
    const float* __restrict__ bih, const float* __restrict__ bhh,
    const float* __restrict__ hin, const int* __restrict__ hsrc,
    float* __restrict__ hout)
{
  int idx = blockIdx.x * 256 + threadIdx.x;
  if (idx >= M * 512) return;
  int m = idx >> 9, i = idx & 511;
  float ir = 0.f, iz = 0.f, inn = 0.f, hr = 0.f, hz = 0.f, hn = 0.f;
  #pragma unroll
  for (int p = 0; p < NPI; p++) {
    const float* g = gip + (long)p * M * 1536 + (long)m * 1536;
    ir += g[i]; iz += g[512 + i]; inn += g[1024 + i];
  }
  #pragma unroll
  for (int p = 0; p < NPH; p++) {
    const float* g = ghp + (long)p * M * 1536 + (long)m * 1536;
    hr += g[i]; hz += g[512 + i]; hn += g[1024 + i];
  }
  ir += bih[i]; iz += bih[512 + i]; inn += bih[1024 + i];
  hr += bhh[i]; hz += bhh[512 + i]; hn += bhh[1024 + i];
  float r = 1.f / (1.f + expf(-(ir + hr)));
  float z = 1.f / (1.f + expf(-(iz + hz)));
  float n = tanhf(inn + r * hn);
  int src = hsrc ? hsrc[m] : m;
  float h = hin[(long)src * 512 + i];
  hout[(long)m * 512 + i] = (1.f - z) * n + z * h;
}

// ---------------- fused logits + per-block (lse-partial, top5-partial) ----------
// grid NVBLK=1000 (32 v each). W staged via global_load_lds double-buffered tiles.
// Partials packed 16 floats (64B) per (blk,row): {m,s,v0..4,i0..4,pad3}.
__global__ __launch_bounds__(256, 4) void logtop_kernel(
    const float* __restrict__ h1, const float* __restrict__ Wout,
    const float* __restrict__ bout, float* __restrict__ PK)
{
  const int tid = threadIdx.x;
  const int ng = tid & 7;
  const int mg = tid >> 3;
  const int blk = blockIdx.x;
  const int v0 = blk * 32;
  const int v = v0 + ng * 4;
  const int m0 = mg * 5;

  __shared__ float Wlds[2][2048];   // [buf][64 k rows x 32 v]
  __shared__ float L[160][33];

  const float* a0 = h1 + (long)m0 * 512;

  const int skk = tid >> 3;
  const int sv4 = tid & 7;
  const float* sg0 = Wout + (size_t)skk * VSZ + v0 + sv4 * 4;
  const float* sg1 = Wout + (size_t)(32 + skk) * VSZ + v0 + sv4 * 4;
  const int lwave = (tid >> 6) * 256;   // this wave's 1KB chunk (in floats)

  auto stage = [&](int tt, int bb) {
    const float* g0 = sg0 + (size_t)tt * 64 * VSZ;
    const float* g1 = sg1 + (size_t)tt * 64 * VSZ;
    __builtin_amdgcn_global_load_lds(
        (const __attribute__((address_space(1))) void*)g0,
        (__attribute__((address_space(3))) void*)&Wlds[bb][lwave], 16, 0, 0);
    __builtin_amdgcn_global_load_lds(
        (const __attribute__((address_space(1))) void*)g1,
        (__attribute__((address_space(3))) void*)&Wlds[bb][1024 + lwave], 16, 0, 0);
  };

  float4 acc[5];
  #pragma unroll
  for (int i = 0; i < 5; i++) acc[i] = make_float4(0.f, 0.f, 0.f, 0.f);

  stage(0, 0);
  __syncthreads();   // drains vmcnt(0) -> tile 0 resident

  float4 aA[5], aB[5];
  #pragma unroll
  for (int i = 0; i < 5; i++) aA[i] = *(const float4*)(a0 + i * 512);

  for (int t8 = 0; t8 < 8; t8++) {
    const float* lb = &Wlds[t8 & 1][0];
    if (t8 < 7) stage(t8 + 1, (t8 + 1) & 1);
    const int kt = t8 * 64;
    #pragma unroll 1
    for (int c = 0; c < 16; c += 2) {
      const int k = kt + c * 4;
      float4 w0[4], w1[4];
      #pragma unroll
      for (int j = 0; j < 4; j++) w0[j] = *(const float4*)&lb[(c * 4 + j) * 32 + ng * 4];
      #pragma unroll
      for (int j = 0; j < 4; j++) w1[j] = *(const float4*)&lb[(c * 4 + 4 + j) * 32 + ng * 4];
      #pragma unroll
      for (int i = 0; i < 5; i++) aB[i] = *(const float4*)(a0 + i * 512 + k + 4);
      #pragma unroll
      for (int i = 0; i < 5; i++) {
        acc[i].x += aA[i].x * w0[0].x + aA[i].y * w0[1].x + aA[i].z * w0[2].x + aA[i].w * w0[3].x;
        acc[i].y += aA[i].x * w0[0].y + aA[i].y * w0[1].y + aA[i].z * w0[2].y + aA[i].w * w0[3].y;
        acc[i].z += aA[i].x * w0[0].z + aA[i].y * w0[1].z + aA[i].z * w0[2].z + aA[i].w * w0[3].z;
        acc[i].w += aA[i].x * w0[0].w + aA[i].y * w0[1].w + aA[i].z * w0[2].w + aA[i].w * w0[3].w;
      }
      int kn = k + 8; if (kn >= 512) kn = 0;   // dummy re-read on last body
      #pragma unroll
      for (int i = 0; i < 5; i++) aA[i] = *(const float4*)(a0 + i * 512 + kn);
      #pragma unroll
      for (int i = 0; i < 5; i++) {
        acc[i].x += aB[i].x * w1[0].x + aB[i].y * w1[1].x + aB[i].z * w1[2].x + aB[i].w * w1[3].x;
        acc[i].y += aB[i].x * w1[0].y + aB[i].y * w1[1].y + aB[i].z * w1[2].y + aB[i].w * w1[3].y;
        acc[i].z += aB[i].x * w1[0].z + aB[i].y * w1[1].z + aB[i].z * w1[2].z + aB[i].w * w1[3].z;
        acc[i].w += aB[i].x * w1[0].w + aB[i].y * w1[1].w + aB[i].z * w1[2].w + aB[i].w * w1[3].w;
      }
    }
    __syncthreads();   // staging for t8+1 landed during the 16-chunk compute
  }

  float4 bb4 = *(const float4*)(bout + v);
  #pragma unroll
  for (int i = 0; i < 5; i++) {
    L[m0 + i][ng * 4 + 0] = acc[i].x + bb4.x;
    L[m0 + i][ng * 4 + 1] = acc[i].y + bb4.y;
    L[m0 + i][ng * 4 + 2] = acc[i].z + bb4.z;
    L[m0 + i][ng * 4 + 3] = acc[i].w + bb4.w;
  }
  __syncthreads();

  if (tid < 160) {
    float m = -3.4e38f, s = 0.f;
    float tv0 = -3.4e38f, tv1 = -3.4e38f, tv2 = -3.4e38f, tv3 = -3.4e38f, tv4 = -3.4e38f;
    int ti0 = 0x7fffffff, ti1 = 0x7fffffff, ti2 = 0x7fffffff, ti3 = 0x7fffffff, ti4 = 0x7fffffff;
    int base = blk * 32;
    for (int c = 0; c < 32; c++) {
      float x = L[tid][c];
      if (x > m) { s *= expf(m - x); m = x; }
      s += expf(x - m);
      INS5(x, base + c);
    }
    float* pk = PK + ((long)blk * 160 + tid) * 16;
    float4 q0 = make_float4(m, s, tv0, tv1);
    float4 q1 = make_float4(tv2, tv3, tv4, __int_as_float(ti0));
    float4 q2 = make_float4(__int_as_float(ti1), __int_as_float(ti2),
                            __int_as_float(ti3), __int_as_float(ti4));
    *(float4*)(pk + 0) = q0;
    *(float4*)(pk + 4) = q1;
    *(float4*)(pk + 8) = q2;
  }
}

// ---------------- row-parallel merge of 1000 packed partials -> RW[row] ---------
// grid 160. lse reduction order identical to the round-3 merge: per-thread
// sequential blk = tid, tid+256, ...; shfl_xor wave tree; sequential 4-wave
// combine. RW[row*16] = {lse, v0..4, i0..4(as float bits), pad}.
__global__ __launch_bounds__(256) void rowmerge_kernel(
    const float* __restrict__ PK, float* __restrict__ RW)
{
  const int row = blockIdx.x, tid = threadIdx.x;
  float m = -3.4e38f, s = 0.f;
  T5 t; t5_init(t);

  for (int it = 0; it < 4; it++) {
    int blk = tid + it * 256;
    if (blk >= NVBLK) break;
    const float* pk = PK + ((long)blk * 160 + row) * 16;
    float4 q0 = *(const float4*)(pk + 0);
    float4 q1 = *(const float4*)(pk + 4);
    float4 q2 = *(const float4*)(pk + 8);
    float nm = fmaxf(m, q0.x);
    s = s * expf(m - nm) + q0.y * expf(q0.x - nm);
    m = nm;
    t5_ins(t, q0.z, __float_as_int(q1.w));
    t5_ins(t, q0.w, __float_as_int(q2.x));
    t5_ins(t, q1.x, __float_as_int(q2.y));
    t5_ins(t, q1.y, __float_as_int(q2.z));
    t5_ins(t, q1.z, __float_as_int(q2.w));
  }

  for (int mask = 1; mask < 64; mask <<= 1) {
    float om = __shfl_xor(m, mask, 64);
    float os = __shfl_xor(s, mask, 64);
    float nm = fmaxf(m, om);
    s = s * expf(m - nm) + os * expf(om - nm);
    m = nm;
    T5 o;
    #pragma unroll
    for (int j = 0; j < 5; j++) {
      o.v[j] = __shfl_xor(t.v[j], mask, 64);
      o.i[j] = __shfl_xor(t.i[j], mask, 64);
    }
    t = t5_merge(t, o);
  }

  __shared__ float wm[4], wss[4], wv[4][5];
  __shared__ int   wi[4][5];
  const int wave = tid >> 6;
  if ((tid & 63) == 0) {
    wm[wave] = m; wss[wave] = s;
    #pragma unroll
    for (int j = 0; j < 5; j++) { wv[wave][j] = t.v[j]; wi[wave][j] = t.i[j]; }
  }
  __syncthreads();
  if (tid == 0) {
    float M2 = wm[0], S2 = wss[0];
    #pragma unroll
    for (int w = 1; w < 4; w++) {
      float nm = fmaxf(M2, wm[w]);
      S2 = S2 * expf(M2 - nm) + wss[w] * expf(wm[w] - nm);
      M2 = nm;
    }
    T5 r;
    #pragma unroll
    for (int j = 0; j < 5; j++) { r.v[j] = wv[0][j]; r.i[j] = wi[0][j]; }
    #pragma unroll
    for (int w = 1; w < 4; w++) {
      T5 o;
      #pragma unroll
      for (int j = 0; j < 5; j++) { o.v[j] = wv[w][j]; o.i[j] = wi[w][j]; }
      r = t5_merge(r, o);
    }
    float* rw = RW + (long)row * 16;
    rw[0] = M2 + logf(S2);
    #pragma unroll
    for (int j = 0; j < 5; j++) {
      rw[1 + j] = r.v[j];
      rw[6 + j] = __int_as_float(r.i[j]);
    }
  }
}

// ---------------- step-0 bookkeeping (row b*KBM only, a = 0) -----------
__global__ void book0_kernel(const float* __restrict__ RW,
                             int* __restrict__ seqs, float* __restrict__ act_ll,
                             int* __restrict__ word_buf, int* __restrict__ hsrc,
                             float* __restrict__ best_ll, int* __restrict__ best_seq)
{
  int b = blockIdx.x, tid = threadIdx.x;
  const float* rw = RW + (long)(b * KBM) * 16;
  float l = rw[0];
  if (tid < SEQL) {
    for (int j = 0; j < KBM; j++) {
      int w = __float_as_int(rw[6 + j]);
      seqs[(b * KBM + j) * SEQL + tid] = (tid == 0) ? 0 : (tid == 1 ? w : 2);
    }
    best_seq[b * SEQL + tid] = 2;
  }
  if (tid < KBM) {
    act_ll[b * KBM + tid] = rw[1 + tid] - l;
    word_buf[b * KBM + tid] = __float_as_int(rw[6 + tid]);
    hsrc[b * KBM + tid] = b * KBM + tid;
  }
  if (tid == 0) best_ll[b] = NEGF;
}

// ---------------- per-step bookkeeping (25-candidate merge folded in) ------------
__global__ void book_kernel(const float* __restrict__ RW,
                            const int* __restrict__ seqs_old, int* __restrict__ seqs_new,
                            float* __restrict__ act_ll, int* __restrict__ word_buf,
                            int* __restrict__ hsrc, float* __restrict__ best_ll,
                            int* __restrict__ best_seq, int t)
{
  int b = blockIdx.x, tid = threadIdx.x;
  __shared__ float sv5[5];
  __shared__ int   si5[5];
  if (tid == 0) {
    T5 g; t5_init(g);
    #pragma unroll
    for (int k = 0; k < KBM; k++) {
      const float* rw = RW + (long)(b * KBM + k) * 16;
      float a = act_ll[b * KBM + k], l = rw[0];
      #pragma unroll
      for (int j = 0; j < 5; j++) {
        float x = a + (rw[1 + j] - l);
        int id = k * VSZ + __float_as_int(rw[6 + j]);
        t5_ins(g, x, id);
      }
    }
    #pragma unroll
    for (int j = 0; j < 5; j++) { sv5[j] = g.v[j]; si5[j] = g.i[j]; }
  }
  __syncthreads();

  __shared__ int ls[KBM][SEQL];
  float v[KBM]; int pr[KBM], wd[KBM];
  #pragma unroll
  for (int j = 0; j < KBM; j++) {
    v[j] = sv5[j];
    int id = si5[j];
    pr[j] = id / VSZ; wd[j] = id % VSZ;
  }
  #pragma unroll
  for (int j = 0; j < KBM; j++) {
    if (tid < SEQL) {
      int x = (tid == t + 1) ? wd[j] : seqs_old[(b * KBM + pr[j]) * SEQL + tid];
      ls[j][tid] = x;
      seqs_new[(b * KBM + j) * SEQL + tid] = x;
    }
  }
  __syncthreads();
  float cll[KBM];
  #pragma unroll
  for (int j = 0; j < KBM; j++) {
    bool fin = v[j] > FINTH;
    bool eos = (wd[j] == 1) && fin;
    cll[j] = eos ? v[j] / (float)(t + 2) : NEGF;
  }
  int jb = 0; float cb = cll[0];
  #pragma unroll
  for (int j = 1; j < KBM; j++) if (cll[j] > cb) { cb = cll[j]; jb = j; }
  bool improve = cb > best_ll[b];
  if (improve) {
    if (tid == 0) best_ll[b] = cb;
    if (tid < SEQL) best_seq[b * SEQL + tid] = ls[jb][tid];
  }
  if (tid < KBM) {
    int j = tid;
    bool fin = v[j] > FINTH;
    bool eos = (wd[j] == 1) && fin;
    act_ll[b * KBM + j] = (fin && !eos) ? v[j] : NEGF;
    word_buf[b * KBM + j] = wd[j];
    hsrc[b * KBM + j] = b * KBM + pr[j];
  }
}

// ---------------- winner selection ----------------
__global__ void final_kernel(const float* __restrict__ best_ll, const int* __restrict__ best_seq,
                             const float* __restrict__ act_ll, const int* __restrict__ seqs,
                             int* __restrict__ out)
{
  int b = blockIdx.x, tid = threadIdx.x;
  bool have = best_ll[b] > FINTH;
  int jb = 0; float ab = act_ll[b * KBM];
  for (int j = 1; j < KBM; j++)
    if (act_ll[b * KBM + j] > ab) { ab = act_ll[b * KBM + j]; jb = j; }
  if (tid < SEQL)
    out[b * SEQL + tid] = have ? best_seq[b * SEQL + tid]
                               : seqs[(b * KBM + jb) * SEQL + tid];
}

extern "C" void kernel_launch(void* const* d_in, const int* in_sizes, int n_in,
                              void* d_out, int out_size, void* d_ws, size_t ws_size,
                              hipStream_t stream)
{
  const int*   source  = (const int*)d_in[0];
  const float* emb_src = (const float*)d_in[1];
  const float* emb_tgt = (const float*)d_in[2];
  const float* eWih = (const float*)d_in[3];
  const float* eWhh = (const float*)d_in[4];
  const float* ebih = (const float*)d_in[5];
  const float* ebhh = (const float*)d_in[6];
  const float* dWih = (const float*)d_in[7];
  const float* dWhh = (const float*)d_in[8];
  const float* dbih = (const float*)d_in[9];
  const float* dbhh = (const float*)d_in[10];
  const float* Wout = (const float*)d_in[11];
  const float* bout = (const float*)d_in[12];
  int* out = (int*)d_out;

  char* ws = (char*)d_ws;
  size_t off = 0;
  auto alloc = [&](size_t bytes) {
    void* p = ws + off;
    off = (off + bytes + 255) & ~(size_t)255;
    return p;
  };
  float* hb0     = (float*)alloc(160 * 512 * 4);
  float* hb1     = (float*)alloc(160 * 512 * 4);
  float* gip     = (float*)alloc((size_t)4 * 160 * 1536 * 4);
  float* ghp     = (float*)alloc((size_t)4 * 160 * 1536 * 4);
  char*  uni     = (char*) alloc((size_t)11 * 1024 * 1024);  // gi_enc aliases PK
  float* gi_enc  = (float*)uni;                              // 1024*1536*4 = 6.29 MB
  float* PK      = (float*)uni;                              // 1000*160*16*4 = 10.24 MB
  float* RW      = (float*)alloc(160 * 16 * 4);
  float* act_ll  = (float*)alloc(160 * 4);
  float* best_ll = (float*)alloc(32 * 4);
  int*   seqs0   = (int*)alloc(160 * SEQL * 4);
  int*   seqs1   = (int*)alloc(160 * SEQL * 4);
  int*   wordb   = (int*)alloc(160 * 4);
  int*   hsrc    = (int*)alloc(160 * 4);
  int*   bseq    = (int*)alloc(32 * SEQL * 4);

  init_kernel<<<64, 256, 0, stream>>>(hb0, wordb, hsrc);

  // ---- encoder: batched gi for all 32 steps, then serial gh + update ----
  genc_kernel<<<dim3(96, 8), 256, 0, stream>>>(emb_src, source, eWih, gi_enc);
  for (int s = 0; s < 32; s++) {
    gates_kernel<1, 1><<<dim3(96, 1, 4), 256, 0, stream>>>(
        nullptr, nullptr, 0, hb0, nullptr, nullptr, eWhh, nullptr, ghp);
    hupd_kernel<1, 4, 32><<<64, 256, 0, stream>>>(
        gi_enc + (size_t)s * 32 * 1536, ghp, ebih, ebhh, hb0, nullptr, hb0);
  }

  // ---- decode step 0 (initial advance) ----
  gates_kernel<5, 0><<<dim3(96, 2, 4), 256, 0, stream>>>(
      emb_tgt, wordb, 1, hb0, hsrc, dWih, dWhh, gip, ghp);
  hupd_kernel<4, 4, 160><<<320, 256, 0, stream>>>(
      gip, ghp, dbih, dbhh, hb0, hsrc, hb1);
  logtop_kernel<<<NVBLK, 256, 0, stream>>>(hb1, Wout, bout, PK);
  rowmerge_kernel<<<160, 256, 0, stream>>>(PK, RW);
  book0_kernel<<<32, 64, 0, stream>>>(RW, seqs0, act_ll, wordb, hsrc,
                                      best_ll, bseq);

  // ---- decode steps t = 1..32 ----
  float* hcur = hb1; float* hoth = hb0;
  int* scur = seqs0; int* soth = seqs1;
  for (int t = 1; t <= 32; t++) {
    gates_kernel<5, 0><<<dim3(96, 2, 4), 256, 0, stream>>>(
        emb_tgt, wordb, 1, hcur, hsrc, dWih, dWhh, gip, ghp);
    hupd_kernel<4, 4, 160><<<320, 256, 0, stream>>>(
        gip, ghp, dbih, dbhh, hcur, hsrc, hoth);
    logtop_kernel<<<NVBLK, 256, 0, stream>>>(hoth, Wout, bout, PK);
    rowmerge_kernel<<<160, 256, 0, stream>>>(PK, RW);
    book_kernel<<<32, 64, 0, stream>>>(RW, scur, soth, act_ll, wordb,
                                       hsrc, best_ll, bseq, t);
    { float* tmp = hcur; hcur = hoth; hoth = tmp; }
    { int* tmp = scur; scur = soth; soth = tmp; }
  }

  final_kernel<<<32, 64, 0, stream>>>(best_ll, bseq, act_ll, scur, out);
}